// Round 8
// baseline (151.876 us; speedup 1.0000x reference)
//
#include <hip/hip_runtime.h>
#include <hip/hip_bf16.h>

// Problem dims
constexpr int BDIM = 16384;  // B (GEMM M)
constexpr int LDIM = 4096;   // L (GEMM N)
constexpr int HDIM = 1024;   // H (GEMM K)

// GEMM tile: 256x256, BK=64 (i8), 8 waves (2Mx4N), wave tile 128x64,
// mfma_i32_32x32x32_i8, 4-slot LDS rings (A and B), 2 barriers per K-tile.
constexpr int BM = 256;
constexpr int BN = 256;
constexpr int BK = 64;
constexpr int KTILES = HDIM / BK;  // 16

typedef __attribute__((ext_vector_type(4))) int i32x4;
typedef __attribute__((ext_vector_type(16))) int i32x16;

// ---------- prep: per-row i8 quant of A and W; bias[j] = W[j].E[j] + b[j] ----------
__global__ void prep_kernel(const float* __restrict__ A, const float* __restrict__ W,
                            const float* __restrict__ E, const float* __restrict__ b,
                            signed char* __restrict__ Aq, signed char* __restrict__ Wq,
                            float* __restrict__ sA, float* __restrict__ sW,
                            float* __restrict__ bias) {
  const int bid = blockIdx.x;
  const int w = threadIdx.x >> 6;
  const int l = threadIdx.x & 63;
  const bool isW = bid < (LDIM / 4);
  const int row = isW ? bid * 4 + w : (bid - LDIM / 4) * 4 + w;
  const float4* s4 = (const float4*)((isW ? W : A) + (size_t)row * HDIM);

  float4 v[4];
  float amax = 0.f, dot = 0.f;
#pragma unroll
  for (int i = 0; i < 4; ++i) {
    v[i] = s4[i * 64 + l];
    amax = fmaxf(amax, fmaxf(fmaxf(fabsf(v[i].x), fabsf(v[i].y)),
                             fmaxf(fabsf(v[i].z), fabsf(v[i].w))));
  }
  if (isW) {
    const float4* e4 = (const float4*)(E + (size_t)row * HDIM);
#pragma unroll
    for (int i = 0; i < 4; ++i) {
      float4 ev = e4[i * 64 + l];
      dot += v[i].x * ev.x + v[i].y * ev.y + v[i].z * ev.z + v[i].w * ev.w;
    }
  }
#pragma unroll
  for (int o = 32; o > 0; o >>= 1) amax = fmaxf(amax, __shfl_xor(amax, o, 64));
  if (isW) {
#pragma unroll
    for (int o = 32; o > 0; o >>= 1) dot += __shfl_xor(dot, o, 64);
  }
  const float inv = amax > 0.f ? 127.f / amax : 0.f;
  unsigned int* dst = (unsigned int*)((isW ? Wq : Aq) + (size_t)row * HDIM);
#pragma unroll
  for (int i = 0; i < 4; ++i) {
    int q0 = (int)rintf(v[i].x * inv), q1 = (int)rintf(v[i].y * inv);
    int q2 = (int)rintf(v[i].z * inv), q3 = (int)rintf(v[i].w * inv);
    dst[i * 64 + l] =
        (q0 & 255) | ((q1 & 255) << 8) | ((q2 & 255) << 16) | ((q3 & 255) << 24);
  }
  if (l == 0) {
    if (isW) { sW[row] = amax * (1.f / 127.f); bias[row] = dot + b[row]; }
    else sA[row] = amax * (1.f / 127.f);
  }
}

// ---------- GEMM: C[B,L] = sA*sW*(Aq[B,H] . Wq[L,H]^T) + bias[L] ----------
__device__ __forceinline__ void gld_lds16(const void* g, void* l) {
  __builtin_amdgcn_global_load_lds(
      (const __attribute__((address_space(1))) void*)g,
      (__attribute__((address_space(3))) void*)l, 16, 0, 0);
}

#define MEMPIN asm volatile("" ::: "memory")
#define SCHED0 __builtin_amdgcn_sched_barrier(0)
#define BAR __builtin_amdgcn_s_barrier()
#define LGKM0 asm volatile("s_waitcnt lgkmcnt(0)" ::: "memory")
#define VM4 asm volatile("s_waitcnt vmcnt(4)" ::: "memory")
#define VM0 asm volatile("s_waitcnt vmcnt(0)" ::: "memory")
#define VMNONE (void)0

__global__ __launch_bounds__(512, 2) void gemm_kernel(
    const signed char* __restrict__ Aq,  // [BDIM, HDIM] i8
    const signed char* __restrict__ Wq,  // [LDIM, HDIM] i8
    const float* __restrict__ sA,        // [BDIM]
    const float* __restrict__ sW,        // [LDIM]
    const float* __restrict__ bias,      // [LDIM]
    float* __restrict__ C)               // [BDIM, LDIM]
{
  // 4-slot rings: 4 x 16KB each for A and B = 128 KiB. 1 block/CU.
  __shared__ __attribute__((aligned(128))) signed char As[4 * BM * BK];
  __shared__ __attribute__((aligned(128))) signed char Bs[4 * BN * BK];

  const int tid = threadIdx.x;
  const int w = tid >> 6;
  const int l = tid & 63;
  const int wr = w >> 2;       // 0..1 : M half (128 rows)
  const int wc = w & 3;        // 0..3 : N quarter (64 cols)
  const int l31 = l & 31;
  const int hi5 = l >> 5;

  // XCD-aware swizzle (1024 blocks, %8==0 -> bijective)
  const int bid = blockIdx.x;
  const int swz = (bid & 7) * 128 + (bid >> 3);
  const int mblk = swz >> 4;   // 64
  const int nblk = swz & 15;   // 16
  const int brow = mblk * BM;
  const int bcol = nblk * BN;

  // staging: one gld_lds16 = 512thr x 16B = 8 KiB = 128 rows x 64B.
  // thread t: row=t>>2, chunk=(t&3)^((row>>1)&3) pre-swizzled (involution).
  const int srow = tid >> 2;                      // 0..127
  const int scn = (tid & 3) ^ ((tid >> 3) & 3);
  const signed char* aSrc = Aq + (size_t)(brow + srow) * HDIM + scn * 16;
  const signed char* bSrc = Wq + (size_t)(bcol + srow) * HDIM + scn * 16;
  const int wdst = w * 1024;  // wave-uniform LDS dest within an 8KB half

  // fragment-read byte offsets within a 64B row.
  // source k-chunk = ks*2 + hi5 (16B of K=32 half for lane-half hi5),
  // LDS chunk = src ^ ((row>>1)&3); (row>>1)&3 == (l31>>1)&3 (bases % 32 == 0)
  const int csw = (l31 >> 1) & 3;
  const int c0 = ((0 + hi5) ^ csw) * 16;  // k-step 0
  const int c1 = ((2 + hi5) ^ csw) * 16;  // k-step 1

  i32x16 acc[4][2] = {};  // [m-frag 32r][n-frag 32c]
  i32x4 aF0[4], aF1[4], bF0[2], bF1[2];

#define ISSUE_A(s, kk)                                                         \
  { const signed char* s_ = aSrc + (kk) * BK;                                  \
    gld_lds16(s_, &As[(s) * 16384 + wdst]);                                    \
    gld_lds16(s_ + (size_t)128 * HDIM, &As[(s) * 16384 + 8192 + wdst]); }
#define ISSUE_B(s, kk)                                                         \
  { const signed char* s_ = bSrc + (kk) * BK;                                  \
    gld_lds16(s_, &Bs[(s) * 16384 + wdst]);                                    \
    gld_lds16(s_ + (size_t)128 * HDIM, &Bs[(s) * 16384 + 8192 + wdst]); }

#define READ6(s, CC, AF, BF)                                                   \
  _Pragma("unroll") for (int mf = 0; mf < 4; ++mf)                             \
    AF[mf] = *(const i32x4*)&As[(s) * 16384 +                                  \
                                (wr * 128 + mf * 32 + l31) * 64 + (CC)];       \
  _Pragma("unroll") for (int nf = 0; nf < 2; ++nf)                             \
    BF[nf] = *(const i32x4*)&Bs[(s) * 16384 +                                  \
                                (wc * 64 + nf * 32 + l31) * 64 + (CC)];

#define MFMA8(AF, BF)                                                          \
  _Pragma("unroll") for (int mf = 0; mf < 4; ++mf) {                           \
    _Pragma("unroll") for (int nf = 0; nf < 2; ++nf) {                         \
      acc[mf][nf] = __builtin_amdgcn_mfma_i32_32x32x32_i8(                     \
          AF[mf], BF[nf], acc[mf][nf], 0, 0, 0);                               \
    }                                                                          \
  }

  // tile t (slot s=t&3): stages A(t+2),B(t+2) -> slot s2=(t+2)&3.
  // 2 barriers/tile; reads issued BEFORE each barrier (latency hides under
  // barrier wait); single counted vmcnt(4) drains tile t+1's loads (issued
  // a full tile ago). Ring distance 2 + drift <1/2 tile => no WAR race.
#define TILE(s, s2, SA, SB, tk2, VMW)                                          \
  { READ6(s, c0, aF0, bF0)                                                     \
    if (SA) ISSUE_A((s2), (tk2));                                              \
    MEMPIN; BAR; LGKM0; SCHED0;                                                \
    __builtin_amdgcn_s_setprio(1);                                             \
    MFMA8(aF0, bF0)                                                            \
    __builtin_amdgcn_s_setprio(0);                                             \
    SCHED0;                                                                    \
    READ6(s, c1, aF1, bF1)                                                     \
    if (SB) ISSUE_B((s2), (tk2));                                              \
    MEMPIN; BAR; LGKM0; SCHED0;                                                \
    __builtin_amdgcn_s_setprio(1);                                             \
    MFMA8(aF1, bF1)                                                            \
    __builtin_amdgcn_s_setprio(0);                                             \
    SCHED0;                                                                    \
    VMW; MEMPIN; }

  // prologue: tiles 0,1 staged to slots 0,1 (order A0,B0,A1,B1);
  // vmcnt(4) -> A0,B0 landed, A1,B1 in flight.
  ISSUE_A(0, 0); ISSUE_B(0, 0); ISSUE_A(1, 1); ISSUE_B(1, 1);
  VM4;
  MEMPIN; BAR;

#pragma unroll 1
  for (int t = 0; t < 12; t += 4) {
    TILE(0, 2, 1, 1, t + 2, VM4);
    TILE(1, 3, 1, 1, t + 3, VM4);
    TILE(2, 0, 1, 1, t + 4, VM4);
    TILE(3, 1, 1, 1, t + 5, VM4);
  }
  TILE(0, 2, 1, 1, 14, VM4);   // t=12
  TILE(1, 3, 1, 1, 15, VM4);   // t=13
  TILE(2, 0, 0, 0, 0, VM0);    // t=14: drain A(15),B(15)
  TILE(3, 1, 0, 0, 0, VMNONE); // t=15

  // epilogue: out = sA[row]*sW[col]*acc + bias[col]
  // C/D layout (32x32, verified): col = lane&31, row = (reg&3)+8*(reg>>2)+4*hi5
  float sw2[2], bv2[2];
#pragma unroll
  for (int nf = 0; nf < 2; ++nf) {
    const int cc = bcol + wc * 64 + nf * 32 + l31;
    sw2[nf] = sW[cc];
    bv2[nf] = bias[cc];
  }
  const int ocol = bcol + wc * 64 + l31;
#pragma unroll
  for (int mf = 0; mf < 4; ++mf) {
    const int rb = brow + wr * 128 + mf * 32 + hi5 * 4;
#pragma unroll
    for (int reg = 0; reg < 16; ++reg) {
      const int row = rb + (reg & 3) + 8 * (reg >> 2);
      const float sa = sA[row];
      const size_t off = (size_t)row * LDIM + ocol;
      C[off]      = (float)acc[mf][0][reg] * (sa * sw2[0]) + bv2[0];
      C[off + 32] = (float)acc[mf][1][reg] * (sa * sw2[1]) + bv2[1];
    }
  }
#undef TILE
#undef MFMA8
#undef READ6
#undef ISSUE_A
#undef ISSUE_B
}

extern "C" void kernel_launch(void* const* d_in, const int* in_sizes, int n_in,
                              void* d_out, int out_size, void* d_ws, size_t ws_size,
                              hipStream_t stream) {
  const float* bert = (const float*)d_in[0];  // [B,H]
  const float* emb  = (const float*)d_in[1];  // [L,H]
  const float* W    = (const float*)d_in[2];  // [L,H]
  const float* b    = (const float*)d_in[3];  // [L]
  float* out = (float*)d_out;

  // ws layout: Aq 16MB | Wq 4MB | sA 64KB | sW 16KB | bias 16KB
  char* ws = (char*)d_ws;
  signed char* Aq = (signed char*)ws;
  signed char* Wq = (signed char*)(ws + (size_t)BDIM * HDIM);
  float* sAp  = (float*)(ws + (size_t)BDIM * HDIM + (size_t)LDIM * HDIM);
  float* sWp  = (float*)((char*)sAp + BDIM * sizeof(float));
  float* bias = (float*)((char*)sWp + LDIM * sizeof(float));

  hipLaunchKernelGGL(prep_kernel, dim3(LDIM / 4 + BDIM / 4), dim3(256), 0, stream,
                     bert, W, emb, b, Aq, Wq, sAp, sWp, bias);
  hipLaunchKernelGGL(gemm_kernel, dim3((BDIM / BM) * (LDIM / BN)), dim3(512), 0, stream,
                     Aq, Wq, sAp, sWp, bias, out);
}

// Round 9
// 137.529 us; speedup vs baseline: 1.1043x; 1.1043x over previous
//
#include <hip/hip_runtime.h>
#include <hip/hip_bf16.h>

// Problem dims
constexpr int BDIM = 16384;  // B (GEMM M)
constexpr int LDIM = 4096;   // L (GEMM N)
constexpr int HDIM = 1024;   // H (GEMM K)

// GEMM tile: 256x128, BK=64 (i8), 8 waves (4Mx2N), wave tile 64x64.
// A: 2-deep dbuf. B: 4-slot ring. ONE barrier per K-tile. (R7 loop, validated.)
// NEW: LDS-transposed float4 epilogue + A-reuse-per-XCD swizzle.
constexpr int BM = 256;
constexpr int BN = 128;
constexpr int BK = 64;
constexpr int KTILES = HDIM / BK;  // 16

typedef __attribute__((ext_vector_type(4))) int i32x4;

// ---------- prep: per-row i8 quant of A and W; bias[j] = W[j].E[j] + b[j] ----------
__global__ void prep_kernel(const float* __restrict__ A, const float* __restrict__ W,
                            const float* __restrict__ E, const float* __restrict__ b,
                            signed char* __restrict__ Aq, signed char* __restrict__ Wq,
                            float* __restrict__ sA, float* __restrict__ sW,
                            float* __restrict__ bias) {
  const int bid = blockIdx.x;
  const int w = threadIdx.x >> 6;
  const int l = threadIdx.x & 63;
  const bool isW = bid < (LDIM / 4);
  const int row = isW ? bid * 4 + w : (bid - LDIM / 4) * 4 + w;
  const float4* s4 = (const float4*)((isW ? W : A) + (size_t)row * HDIM);

  float4 v[4];
  float amax = 0.f, dot = 0.f;
#pragma unroll
  for (int i = 0; i < 4; ++i) {
    v[i] = s4[i * 64 + l];
    amax = fmaxf(amax, fmaxf(fmaxf(fabsf(v[i].x), fabsf(v[i].y)),
                             fmaxf(fabsf(v[i].z), fabsf(v[i].w))));
  }
  if (isW) {
    const float4* e4 = (const float4*)(E + (size_t)row * HDIM);
#pragma unroll
    for (int i = 0; i < 4; ++i) {
      float4 ev = e4[i * 64 + l];
      dot += v[i].x * ev.x + v[i].y * ev.y + v[i].z * ev.z + v[i].w * ev.w;
    }
  }
#pragma unroll
  for (int o = 32; o > 0; o >>= 1) amax = fmaxf(amax, __shfl_xor(amax, o, 64));
  if (isW) {
#pragma unroll
    for (int o = 32; o > 0; o >>= 1) dot += __shfl_xor(dot, o, 64);
  }
  const float inv = amax > 0.f ? 127.f / amax : 0.f;
  unsigned int* dst = (unsigned int*)((isW ? Wq : Aq) + (size_t)row * HDIM);
#pragma unroll
  for (int i = 0; i < 4; ++i) {
    int q0 = (int)rintf(v[i].x * inv), q1 = (int)rintf(v[i].y * inv);
    int q2 = (int)rintf(v[i].z * inv), q3 = (int)rintf(v[i].w * inv);
    dst[i * 64 + l] =
        (q0 & 255) | ((q1 & 255) << 8) | ((q2 & 255) << 16) | ((q3 & 255) << 24);
  }
  if (l == 0) {
    if (isW) { sW[row] = amax * (1.f / 127.f); bias[row] = dot + b[row]; }
    else sA[row] = amax * (1.f / 127.f);
  }
}

// ---------- GEMM: C[B,L] = sA*sW*(Aq[B,H] . Wq[L,H]^T) + bias[L] ----------
__device__ __forceinline__ void gld_lds16(const void* g, void* l) {
  __builtin_amdgcn_global_load_lds(
      (const __attribute__((address_space(1))) void*)g,
      (__attribute__((address_space(3))) void*)l, 16, 0, 0);
}

#define MEMPIN asm volatile("" ::: "memory")
#define SCHED0 __builtin_amdgcn_sched_barrier(0)
#define BAR __builtin_amdgcn_s_barrier()
#define LGKM0 asm volatile("s_waitcnt lgkmcnt(0)" ::: "memory")
#define VM1 asm volatile("s_waitcnt vmcnt(1)" ::: "memory")
#define VM0 asm volatile("s_waitcnt vmcnt(0)" ::: "memory")
#define VMNONE (void)0

__global__ __launch_bounds__(512, 4) void gemm_kernel(
    const signed char* __restrict__ Aq,  // [BDIM, HDIM] i8
    const signed char* __restrict__ Wq,  // [LDIM, HDIM] i8
    const float* __restrict__ sA,        // [BDIM]
    const float* __restrict__ sW,        // [LDIM]
    const float* __restrict__ bias,      // [LDIM]
    float* __restrict__ C)               // [BDIM, LDIM]
{
  // One 64KB LDS pool: As = 2x16KB dbuf, Bs = 4x8KB ring; reused as the
  // f32 transpose tile (64 x 132) in the epilogue. 2 blocks/CU.
  __shared__ __attribute__((aligned(128))) signed char LDSU[65536];
  signed char* As = LDSU;            // 32 KiB
  signed char* Bs = LDSU + 32768;    // 32 KiB

  const int tid = threadIdx.x;
  const int w = tid >> 6;
  const int l = tid & 63;
  const int wr = w >> 1;       // 0..3 : M quarter (64 rows)
  const int wc = w & 1;        // 0..1 : N half (64 cols)
  const int lr = l & 15;
  const int hi = l >> 4;

  // A-reuse-per-XCD swizzle: XCD x owns mblks {8x..8x+7} (A 2MB L2-pinned),
  // sweeps all 32 nblks (B 4MB via L2/L3). Bijective over 2048 blocks.
  const int bid = blockIdx.x;
  const int mblk = (bid & 7) * 8 + (bid >> 8);   // 0..63
  const int nblk = (bid >> 3) & 31;              // 0..31
  const int brow = mblk * BM;
  const int bcol = nblk * BN;

  // staging: one gld_lds16 = 512thr x 16B = 8 KiB = 128 rows x 64B.
  // thread t: row=t>>2, chunk=(t&3)^((row>>1)&3) pre-swizzled (involution).
  const int srow = tid >> 2;                      // 0..127
  const int scn = (tid & 3) ^ ((tid >> 3) & 3);
  const signed char* aSrc = Aq + (size_t)(brow + srow) * HDIM + scn * 16;
  const signed char* bSrc = Wq + (size_t)(bcol + srow) * HDIM + scn * 16;

  // fragment-read byte offset within a 64B row (same XOR on read side)
  const int c0 = (hi ^ ((lr >> 1) & 3)) * 16;
  const int rowA = wr * 64 + lr;
  const int rowB = wc * 64 + lr;

  i32x4 acc[4][4] = {};
  i32x4 aF[4], bF[4];

#define ISSUE_A(d, kk)                                                         \
  { const signed char* s_ = aSrc + (kk) * BK;                                  \
    gld_lds16(s_, &As[(d) * 16384 + w * 1024]);                                \
    gld_lds16(s_ + (size_t)128 * HDIM, &As[(d) * 16384 + 8192 + w * 1024]); }
#define ISSUE_B(s, kk)                                                         \
  gld_lds16(bSrc + (kk) * BK, &Bs[(s) * 8192 + w * 1024]);

#define READ_AB(d, s)                                                          \
  _Pragma("unroll") for (int mi = 0; mi < 4; ++mi)                             \
    aF[mi] = *(const i32x4*)&As[(d) * 16384 + (rowA + mi * 16) * 64 + c0];     \
  _Pragma("unroll") for (int ni = 0; ni < 4; ++ni)                             \
    bF[ni] = *(const i32x4*)&Bs[(s) * 8192 + (rowB + ni * 16) * 64 + c0];

#define MFMA16                                                                 \
  _Pragma("unroll") for (int mi = 0; mi < 4; ++mi) {                           \
    _Pragma("unroll") for (int ni = 0; ni < 4; ++ni) {                         \
      acc[mi][ni] = __builtin_amdgcn_mfma_i32_16x16x64_i8(                     \
          aF[mi], bF[ni], acc[mi][ni], 0, 0, 0);                               \
    }                                                                          \
  }

#define TILE(d, s, SA, tA, SB, sB, tB, VMW, DOBAR)                             \
  { READ_AB(d, s)                                                              \
    if (SA) ISSUE_A((d) ^ 1, (tA));                                            \
    SCHED0; LGKM0; SCHED0;                                                     \
    __builtin_amdgcn_s_setprio(1);                                             \
    MFMA16                                                                     \
    __builtin_amdgcn_s_setprio(0);                                             \
    SCHED0;                                                                    \
    if (SB) ISSUE_B((sB), (tB));                                               \
    VMW; MEMPIN;                                                               \
    if (DOBAR) BAR;                                                            \
    MEMPIN; }

  // prologue: A(0)->buf0 (2 loads), B(0)->slot0, B(1)->slot1.
  ISSUE_A(0, 0); ISSUE_B(0, 0); ISSUE_B(1, 1);
  VM1;
  MEMPIN; BAR;

#pragma unroll 1
  for (int t = 0; t < 12; t += 4) {
    TILE(0, 0, 1, t + 1, 1, 2, t + 2, VM1, 1);
    TILE(1, 1, 1, t + 2, 1, 3, t + 3, VM1, 1);
    TILE(0, 2, 1, t + 3, 1, 0, t + 4, VM1, 1);
    TILE(1, 3, 1, t + 4, 1, 1, t + 5, VM1, 1);
  }
  TILE(0, 0, 1, 13, 1, 2, 14, VM1, 1);
  TILE(1, 1, 1, 14, 1, 3, 15, VM1, 1);
  TILE(0, 2, 1, 15, 0, 0, 0, VM0, 1);
  TILE(1, 3, 0, 0, 0, 0, 0, VMNONE, 0);

  // ---- epilogue: dequant + LDS transpose -> contiguous float4 stores ----
  float sw4[4], bv[4];
#pragma unroll
  for (int ni = 0; ni < 4; ++ni) {
    const int cc = bcol + wc * 64 + ni * 16 + lr;
    sw4[ni] = sW[cc];
    bv[ni] = bias[cc];
  }
  MEMPIN; BAR;  // all waves done with As/Bs tile reads before reuse as T
  float* T = (float*)LDSU;  // 64 rows x 132 floats (pad 4) = 33 KiB

#pragma unroll
  for (int c = 0; c < 4; ++c) {
    // each wave writes its frag-row mi=c: 16 global rows, its 64-col half.
#pragma unroll
    for (int r = 0; r < 4; ++r) {
      const int grow = brow + wr * 64 + c * 16 + hi * 4 + r;
      const float sa = sA[grow];
      const int trow = wr * 16 + hi * 4 + r;  // 0..63
#pragma unroll
      for (int ni = 0; ni < 4; ++ni) {
        T[trow * 132 + wc * 64 + ni * 16 + lr] =
            (float)acc[c][ni][r] * (sa * sw4[ni]) + bv[ni];
      }
    }
    MEMPIN; BAR;
    // all 512 lanes store 4 units: 64 rows x 32 float4-cols; each store
    // instr = 2 rows x 512B contiguous.
#pragma unroll
    for (int k = 0; k < 4; ++k) {
      const int u = w * 64 + l + k * 512;
      const int row = u >> 5, c4 = u & 31;
      const int grow = brow + (row >> 4) * 64 + c * 16 + (row & 15);
      float4 v = *(const float4*)&T[row * 132 + c4 * 4];
      *(float4*)&C[(size_t)grow * LDIM + bcol + c4 * 4] = v;
    }
    MEMPIN; BAR;
  }
#undef TILE
#undef MFMA16
#undef READ_AB
#undef ISSUE_A
#undef ISSUE_B
}

extern "C" void kernel_launch(void* const* d_in, const int* in_sizes, int n_in,
                              void* d_out, int out_size, void* d_ws, size_t ws_size,
                              hipStream_t stream) {
  const float* bert = (const float*)d_in[0];  // [B,H]
  const float* emb  = (const float*)d_in[1];  // [L,H]
  const float* W    = (const float*)d_in[2];  // [L,H]
  const float* b    = (const float*)d_in[3];  // [L]
  float* out = (float*)d_out;

  // ws layout: Aq 16MB | Wq 4MB | sA 64KB | sW 16KB | bias 16KB
  char* ws = (char*)d_ws;
  signed char* Aq = (signed char*)ws;
  signed char* Wq = (signed char*)(ws + (size_t)BDIM * HDIM);
  float* sAp  = (float*)(ws + (size_t)BDIM * HDIM + (size_t)LDIM * HDIM);
  float* sWp  = (float*)((char*)sAp + BDIM * sizeof(float));
  float* bias = (float*)((char*)sWp + LDIM * sizeof(float));

  hipLaunchKernelGGL(prep_kernel, dim3(LDIM / 4 + BDIM / 4), dim3(256), 0, stream,
                     bert, W, emb, b, Aq, Wq, sAp, sWp, bias);
  hipLaunchKernelGGL(gemm_kernel, dim3((BDIM / BM) * (LDIM / BN)), dim3(512), 0, stream,
                     Aq, Wq, sAp, sWp, bias, out);
}

// Round 10
// 136.458 us; speedup vs baseline: 1.1130x; 1.0078x over previous
//
#include <hip/hip_runtime.h>
#include <hip/hip_bf16.h>

// Problem dims
constexpr int BDIM = 16384;  // B (GEMM M)
constexpr int LDIM = 4096;   // L (GEMM N)
constexpr int HDIM = 1024;   // H (GEMM K)

// GEMM tile: 256x128, BK=64 (i8), 8 waves (4Mx2N), wave tile 64x64.
// A and B both in 3-slot LDS rings, stage distance 2 (full-region latency
// slack for every load). ONE barrier + ONE counted vmcnt per K-tile.
// 72 KiB LDS -> 2 blocks/CU.
constexpr int BM = 256;
constexpr int BN = 128;
constexpr int BK = 64;
constexpr int KTILES = HDIM / BK;  // 16

typedef __attribute__((ext_vector_type(4))) int i32x4;

// ---------- prep: per-row i8 quant of A and W; bias[j] = W[j].E[j] + b[j] ----------
__global__ void prep_kernel(const float* __restrict__ A, const float* __restrict__ W,
                            const float* __restrict__ E, const float* __restrict__ b,
                            signed char* __restrict__ Aq, signed char* __restrict__ Wq,
                            float* __restrict__ sA, float* __restrict__ sW,
                            float* __restrict__ bias) {
  const int bid = blockIdx.x;
  const int w = threadIdx.x >> 6;
  const int l = threadIdx.x & 63;
  const bool isW = bid < (LDIM / 4);
  const int row = isW ? bid * 4 + w : (bid - LDIM / 4) * 4 + w;
  const float4* s4 = (const float4*)((isW ? W : A) + (size_t)row * HDIM);

  float4 v[4];
  float amax = 0.f, dot = 0.f;
#pragma unroll
  for (int i = 0; i < 4; ++i) {
    v[i] = s4[i * 64 + l];
    amax = fmaxf(amax, fmaxf(fmaxf(fabsf(v[i].x), fabsf(v[i].y)),
                             fmaxf(fabsf(v[i].z), fabsf(v[i].w))));
  }
  if (isW) {
    const float4* e4 = (const float4*)(E + (size_t)row * HDIM);
#pragma unroll
    for (int i = 0; i < 4; ++i) {
      float4 ev = e4[i * 64 + l];
      dot += v[i].x * ev.x + v[i].y * ev.y + v[i].z * ev.z + v[i].w * ev.w;
    }
  }
#pragma unroll
  for (int o = 32; o > 0; o >>= 1) amax = fmaxf(amax, __shfl_xor(amax, o, 64));
  if (isW) {
#pragma unroll
    for (int o = 32; o > 0; o >>= 1) dot += __shfl_xor(dot, o, 64);
  }
  const float inv = amax > 0.f ? 127.f / amax : 0.f;
  unsigned int* dst = (unsigned int*)((isW ? Wq : Aq) + (size_t)row * HDIM);
#pragma unroll
  for (int i = 0; i < 4; ++i) {
    int q0 = (int)rintf(v[i].x * inv), q1 = (int)rintf(v[i].y * inv);
    int q2 = (int)rintf(v[i].z * inv), q3 = (int)rintf(v[i].w * inv);
    dst[i * 64 + l] =
        (q0 & 255) | ((q1 & 255) << 8) | ((q2 & 255) << 16) | ((q3 & 255) << 24);
  }
  if (l == 0) {
    if (isW) { sW[row] = amax * (1.f / 127.f); bias[row] = dot + b[row]; }
    else sA[row] = amax * (1.f / 127.f);
  }
}

// ---------- GEMM: C[B,L] = sA*sW*(Aq[B,H] . Wq[L,H]^T) + bias[L] ----------
__device__ __forceinline__ void gld_lds16(const void* g, void* l) {
  __builtin_amdgcn_global_load_lds(
      (const __attribute__((address_space(1))) void*)g,
      (__attribute__((address_space(3))) void*)l, 16, 0, 0);
}

#define MEMPIN asm volatile("" ::: "memory")
#define SCHED0 __builtin_amdgcn_sched_barrier(0)
#define BAR __builtin_amdgcn_s_barrier()
#define LGKM0 asm volatile("s_waitcnt lgkmcnt(0)" ::: "memory")
#define VM3 asm volatile("s_waitcnt vmcnt(3)" ::: "memory")
#define VM0 asm volatile("s_waitcnt vmcnt(0)" ::: "memory")
#define VMNONE (void)0

__global__ __launch_bounds__(512, 4) void gemm_kernel(
    const signed char* __restrict__ Aq,  // [BDIM, HDIM] i8
    const signed char* __restrict__ Wq,  // [LDIM, HDIM] i8
    const float* __restrict__ sA,        // [BDIM]
    const float* __restrict__ sW,        // [LDIM]
    const float* __restrict__ bias,      // [LDIM]
    float* __restrict__ C)               // [BDIM, LDIM]
{
  // As: 3 x 16KB ring. Bs: 3 x 8KB ring. 72 KiB total -> 2 blocks/CU.
  __shared__ __attribute__((aligned(128))) signed char As[3 * BM * BK];
  __shared__ __attribute__((aligned(128))) signed char Bs[3 * BN * BK];

  const int tid = threadIdx.x;
  const int w = tid >> 6;
  const int l = tid & 63;
  const int wr = w >> 1;       // 0..3 : M quarter (64 rows)
  const int wc = w & 1;        // 0..1 : N half (64 cols)
  const int lr = l & 15;
  const int hi = l >> 4;

  // XCD-aware swizzle (2048 blocks, %8==0 -> bijective), nblk inner (R7).
  const int bid = blockIdx.x;
  const int swz = (bid & 7) * 256 + (bid >> 3);
  const int mblk = swz >> 5;   // 64
  const int nblk = swz & 31;   // 32
  const int brow = mblk * BM;
  const int bcol = nblk * BN;

  // staging: one gld_lds16 = 512thr x 16B = 8 KiB = 128 rows x 64B.
  // thread t: row=t>>2, chunk=(t&3)^((row>>1)&3) pre-swizzled (involution).
  const int srow = tid >> 2;                      // 0..127
  const int scn = (tid & 3) ^ ((tid >> 3) & 3);
  const signed char* aSrc = Aq + (size_t)(brow + srow) * HDIM + scn * 16;
  const signed char* bSrc = Wq + (size_t)(bcol + srow) * HDIM + scn * 16;

  // fragment-read byte offset within a 64B row (same XOR on read side)
  const int c0 = (hi ^ ((lr >> 1) & 3)) * 16;
  const int rowA = wr * 64 + lr;
  const int rowB = wc * 64 + lr;

  i32x4 acc[4][4] = {};
  i32x4 aF[4], bF[4];

#define ISSUE_A(s, kk)                                                         \
  { const signed char* s_ = aSrc + (kk) * BK;                                  \
    gld_lds16(s_, &As[(s) * 16384 + w * 1024]);                                \
    gld_lds16(s_ + (size_t)128 * HDIM, &As[(s) * 16384 + 8192 + w * 1024]); }
#define ISSUE_B(s, kk)                                                         \
  gld_lds16(bSrc + (kk) * BK, &Bs[(s) * 8192 + w * 1024]);

#define READ_AB(s)                                                             \
  _Pragma("unroll") for (int mi = 0; mi < 4; ++mi)                             \
    aF[mi] = *(const i32x4*)&As[(s) * 16384 + (rowA + mi * 16) * 64 + c0];     \
  _Pragma("unroll") for (int ni = 0; ni < 4; ++ni)                             \
    bF[ni] = *(const i32x4*)&Bs[(s) * 8192 + (rowB + ni * 16) * 64 + c0];

#define MFMA16                                                                 \
  _Pragma("unroll") for (int mi = 0; mi < 4; ++mi) {                           \
    _Pragma("unroll") for (int ni = 0; ni < 4; ++ni) {                         \
      acc[mi][ni] = __builtin_amdgcn_mfma_i32_16x16x64_i8(                     \
          aF[mi], bF[ni], acc[mi][ni], 0, 0, 0);                               \
    }                                                                          \
  }

  // region t (read slot s=t%3): issue tile t+2 (A:2 loads, B:1) -> slot
  // s2=(t+2)%3 at region TOP (2 full regions of latency slack); ds_read this
  // tile; lgkm0; 16 MFMA; counted vmcnt(3) ensures tile t+1 landed (its 3
  // loads were issued a full region ago); ONE barrier.
  // Race audit: writer slot (t+2)%3 vs concurrent readers t%3,(t+1)%3 --
  // disjoint mod 3; drift bounded by the single barrier.
#define TILE(s, s2, SS, tk2, VMW, DOBAR)                                       \
  { READ_AB(s)                                                                 \
    if (SS) { ISSUE_A((s2), (tk2)); ISSUE_B((s2), (tk2)); }                    \
    SCHED0; LGKM0; SCHED0;                                                     \
    __builtin_amdgcn_s_setprio(1);                                             \
    MFMA16                                                                     \
    __builtin_amdgcn_s_setprio(0);                                             \
    SCHED0;                                                                    \
    VMW; MEMPIN;                                                               \
    if (DOBAR) BAR;                                                            \
    MEMPIN; }

  // prologue: tiles 0,1 -> slots 0,1 (A0,B0,A1,B1). vmcnt(3): tile 0 landed,
  // tile 1's 3 loads in flight.
  ISSUE_A(0, 0); ISSUE_B(0, 0); ISSUE_A(1, 1); ISSUE_B(1, 1);
  VM3;
  MEMPIN; BAR;

  // regions 0..11 (period 3), staging tiles 2..13
#pragma unroll 1
  for (int t = 0; t < 12; t += 3) {
    TILE(0, 2, 1, t + 2, VM3, 1);
    TILE(1, 0, 1, t + 3, VM3, 1);
    TILE(2, 1, 1, t + 4, VM3, 1);
  }
  // regions 12..15: stage tiles 14,15 then drain
  TILE(0, 2, 1, 14, VM3, 1);
  TILE(1, 0, 1, 15, VM3, 1);
  TILE(2, 0, 0, 0, VM0, 1);
  TILE(0, 0, 0, 0, VMNONE, 0);

  // epilogue: dequant out = sA[r]*sW[c]*acc + bias[c]  (R7 direct store)
  float sw4[4], bv[4];
#pragma unroll
  for (int ni = 0; ni < 4; ++ni) {
    const int cc = bcol + wc * 64 + ni * 16 + lr;
    sw4[ni] = sW[cc];
    bv[ni] = bias[cc];
  }
  const int orow0 = brow + wr * 64 + hi * 4;
  const int ocol0 = bcol + wc * 64 + lr;
#pragma unroll
  for (int mi = 0; mi < 4; ++mi) {
#pragma unroll
    for (int r = 0; r < 4; ++r) {
      const float sa = sA[orow0 + mi * 16 + r];
#pragma unroll
      for (int ni = 0; ni < 4; ++ni) {
        C[(size_t)(orow0 + mi * 16 + r) * LDIM + ocol0 + ni * 16] =
            (float)acc[mi][ni][r] * (sa * sw4[ni]) + bv[ni];
      }
    }
  }
#undef TILE
#undef MFMA16
#undef READ_AB
#undef ISSUE_A
#undef ISSUE_B
}

extern "C" void kernel_launch(void* const* d_in, const int* in_sizes, int n_in,
                              void* d_out, int out_size, void* d_ws, size_t ws_size,
                              hipStream_t stream) {
  const float* bert = (const float*)d_in[0];  // [B,H]
  const float* emb  = (const float*)d_in[1];  // [L,H]
  const float* W    = (const float*)d_in[2];  // [L,H]
  const float* b    = (const float*)d_in[3];  // [L]
  float* out = (float*)d_out;

  // ws layout: Aq 16MB | Wq 4MB | sA 64KB | sW 16KB | bias 16KB
  char* ws = (char*)d_ws;
  signed char* Aq = (signed char*)ws;
  signed char* Wq = (signed char*)(ws + (size_t)BDIM * HDIM);
  float* sAp  = (float*)(ws + (size_t)BDIM * HDIM + (size_t)LDIM * HDIM);
  float* sWp  = (float*)((char*)sAp + BDIM * sizeof(float));
  float* bias = (float*)((char*)sWp + LDIM * sizeof(float));

  hipLaunchKernelGGL(prep_kernel, dim3(LDIM / 4 + BDIM / 4), dim3(256), 0, stream,
                     bert, W, emb, b, Aq, Wq, sAp, sWp, bias);
  hipLaunchKernelGGL(gemm_kernel, dim3((BDIM / BM) * (LDIM / BN)), dim3(512), 0, stream,
                     Aq, Wq, sAp, sWp, bias, out);
}